// Round 21
// baseline (170.740 us; speedup 1.0000x reference)
//
#include <hip/hip_runtime.h>
#include <stdint.h>

typedef unsigned short u16;
typedef __attribute__((ext_vector_type(4))) float f32x4;
typedef __attribute__((ext_vector_type(8))) short bf16x8;

#define NTOK 8192
#define DDIM 1024
#define FDIM 1024
#define NEXP 8
#define PCAP 8192
#define RBLK 512  // router sub-grid

// ---- device-global scratch -------------------------------------------------
__device__ __align__(256) u16 g_xb[NTOK * DDIM];          // x cast to bf16
__device__ __align__(256) u16 g_wbf[NEXP * FDIM * DDIM];  // expert_w bf16
__device__ __align__(256) u16 g_buf0[NTOK * FDIM];        // k=0 contrib (bf16)
__device__ __align__(256) u16 g_buf1[NTOK * FDIM];        // k=1 contrib (bf16)
__device__ __align__(256) int g_ptok[NEXP * PCAP];
__device__ __align__(256) float g_pw[NEXP * PCAP];
__device__ __align__(256) unsigned g_e01[NTOK];  // packed e0|e1<<8
__device__ __align__(256) float g_w0[NTOK];      // renorm top1 weight
__device__ __align__(256) float g_w1[NTOK];      // renorm top2 weight
__device__ __align__(256) float g_usage_part[NEXP * RBLK];  // [e][block]
__device__ __align__(256) float g_gram_part[36 * RBLK];     // [gi][block]
__device__ __align__(256) unsigned g_tile[160];  // XCD-affine worklist
__device__ int g_cnt[16];

__device__ __forceinline__ u16 f2bf(float f) {
  unsigned u = __builtin_bit_cast(unsigned, f);
  unsigned r = u + 0x7fffu + ((u >> 16) & 1u);  // RNE
  return (u16)(r >> 16);
}

__device__ __forceinline__ float b2f(unsigned h) {
  return __builtin_bit_cast(float, h << 16);
}

__device__ __forceinline__ void gload_lds16(const void* g, void* l) {
  __builtin_amdgcn_global_load_lds(
      (const __attribute__((address_space(1))) void*)g,
      (__attribute__((address_space(3))) void*)l, 16, 0, 0);
}

// ---------------------------------------------------------------------------
// Fused pre-pass. Blocks 0..511: router. Blocks 512..1023: gram + cast.
// Partials written TRANSPOSED: [entry][block] for coalesced reduction.
// ---------------------------------------------------------------------------
__global__ __launch_bounds__(256) void k_pre(const float* __restrict__ x,
                                             const float* __restrict__ rwg,
                                             const float* __restrict__ rb,
                                             const float* __restrict__ ew,
                                             const float* __restrict__ ebias,
                                             const float* __restrict__ epref,
                                             float* __restrict__ rwout) {
  const int tid = threadIdx.x;
  if (blockIdx.x >= RBLK) {
    // ---------------- gram + cast path ----------------
    const int bid = blockIdx.x - RBLK;
    const int P0 = FDIM * DDIM;
    const int PT = P0 + FDIM + DDIM;
    float g[36];
#pragma unroll
    for (int i = 0; i < 36; ++i) g[i] = 0.f;
    for (int k = bid * 256 + tid; k < PT; k += RBLK * 256) {
      float v[8];
      if (k < P0) {
#pragma unroll
        for (int e = 0; e < 8; ++e) v[e] = ew[(size_t)e * P0 + k];
#pragma unroll
        for (int e = 0; e < 8; ++e) g_wbf[(size_t)e * P0 + k] = f2bf(v[e]);
      } else if (k < P0 + FDIM) {
        int kk = k - P0;
#pragma unroll
        for (int e = 0; e < 8; ++e) v[e] = ebias[e * FDIM + kk];
      } else {
        int kk = k - P0 - FDIM;
#pragma unroll
        for (int e = 0; e < 8; ++e) v[e] = epref[e * DDIM + kk];
      }
      int idx = 0;
#pragma unroll
      for (int i = 0; i < 8; ++i)
#pragma unroll
        for (int j = i; j < 8; ++j) {
          g[idx] += v[i] * v[j];
          ++idx;
        }
    }
#pragma unroll
    for (int i = 0; i < 36; ++i) {
      float a = g[i];
#pragma unroll
      for (int s = 32; s; s >>= 1) a += __shfl_xor(a, s);
      g[i] = a;
    }
    __shared__ float gs[4][36];
    const int w = tid >> 6, lane = tid & 63;
    if (lane == 0) {
#pragma unroll
      for (int i = 0; i < 36; ++i) gs[w][i] = g[i];
    }
    __syncthreads();
    if (tid < 36)
      g_gram_part[tid * RBLK + bid] =
          gs[0][tid] + gs[1][tid] + gs[2][tid] + gs[3][tid];
    return;
  }
  // ---------------- router path ----------------
  __shared__ __align__(16) float rw_lds[NEXP * DDIM];
  __shared__ float us[NEXP];
  const int w = tid >> 6, lane = tid & 63;
  {
    const float4* src = (const float4*)rwg;
    float4* dst = (float4*)rw_lds;
#pragma unroll
    for (int i = 0; i < 8; ++i) dst[tid + 256 * i] = src[tid + 256 * i];
  }
  if (tid < NEXP) us[tid] = 0.f;
  __syncthreads();

  float rbl[NEXP];
#pragma unroll
  for (int e = 0; e < NEXP; ++e) rbl[e] = rb[e];
  float uw[NEXP];
#pragma unroll
  for (int e = 0; e < NEXP; ++e) uw[e] = 0.f;

  for (int it = 0; it < 4; ++it) {
    const int t = blockIdx.x * 16 + w * 4 + it;
    const float4* xv = (const float4*)(x + (size_t)t * DDIM);
    float4 xv4[4];
#pragma unroll
    for (int j = 0; j < 4; ++j) xv4[j] = xv[lane + 64 * j];
    ushort4* xo = (ushort4*)(g_xb + (size_t)t * DDIM);
#pragma unroll
    for (int j = 0; j < 4; ++j) {
      float4 v = xv4[j];
      ushort4 o;
      o.x = f2bf(v.x); o.y = f2bf(v.y); o.z = f2bf(v.z); o.w = f2bf(v.w);
      xo[lane + 64 * j] = o;
    }
    float lg[NEXP];
#pragma unroll
    for (int e = 0; e < NEXP; ++e) {
      float a = 0.f;
#pragma unroll
      for (int j = 0; j < 4; ++j) {
        float4 r = *(const float4*)&rw_lds[e * DDIM + (lane + 64 * j) * 4];
        float4 v = xv4[j];
        a += v.x * r.x + v.y * r.y + v.z * r.z + v.w * r.w;
      }
      lg[e] = a;
    }
#pragma unroll
    for (int e = 0; e < NEXP; ++e) {
      float a = lg[e];
#pragma unroll
      for (int s = 32; s; s >>= 1) a += __shfl_xor(a, s);
      lg[e] = a + rbl[e];
    }
    float mx = lg[0];
#pragma unroll
    for (int e = 1; e < NEXP; ++e) mx = fmaxf(mx, lg[e]);
    float p[NEXP];
    float sm = 0.f;
#pragma unroll
    for (int e = 0; e < NEXP; ++e) {
      p[e] = expf(lg[e] - mx);
      sm += p[e];
    }
    float inv = 1.f / sm;
#pragma unroll
    for (int e = 0; e < NEXP; ++e) {
      p[e] *= inv;
      uw[e] += p[e];
    }
    int e0 = 0;
    float b0 = p[0];
#pragma unroll
    for (int e = 1; e < NEXP; ++e)
      if (p[e] > b0) { b0 = p[e]; e0 = e; }
    int e1 = -1;
    float b1 = -1.f;
#pragma unroll
    for (int e = 0; e < NEXP; ++e)
      if (e != e0 && p[e] > b1) { b1 = p[e]; e1 = e; }
    if (lane == 0) {
      float4* rw4 = (float4*)(rwout + (size_t)t * NEXP);
      rw4[0] = make_float4(p[0], p[1], p[2], p[3]);
      rw4[1] = make_float4(p[4], p[5], p[6], p[7]);
      float rn = 1.f / (b0 + b1);
      g_e01[t] = (unsigned)e0 | ((unsigned)e1 << 8);
      g_w0[t] = b0 * rn;
      g_w1[t] = b1 * rn;
    }
  }
  if (lane == 0) {
#pragma unroll
    for (int e = 0; e < NEXP; ++e) atomicAdd(&us[e], uw[e]);  // LDS atomic only
  }
  __syncthreads();
  if (tid < NEXP) g_usage_part[tid * RBLK + blockIdx.x] = us[tid];
}

// ---------------------------------------------------------------------------
// Blocks 0..7: list build (e01 preloaded to registers; double-buffered wcnt).
// Block 8: stats (unrolled coalesced reductions) + XCD-affine worklist
// (128-row M-slots — R19 geometry).
// ---------------------------------------------------------------------------
__global__ __launch_bounds__(256) void k_lists(float* __restrict__ out_util,
                                               float* __restrict__ out_lbl,
                                               float* __restrict__ out_div) {
  const int tid = threadIdx.x;
  const int wv = tid >> 6, lane = tid & 63;
  if (blockIdx.x == 8) {
    __shared__ int hw[4][8];
    __shared__ int hist[8];
    __shared__ int s_nt[8], s_placed[8];
    __shared__ float su[8];
    __shared__ float sg[36];
    int cnt[8];
#pragma unroll
    for (int e = 0; e < 8; ++e) cnt[e] = 0;
#pragma unroll 8
    for (int t = tid; t < NTOK; t += 256) {
      unsigned rec = g_e01[t];
      int ea = (int)(rec & 255u), ebx = (int)((rec >> 8) & 255u);
#pragma unroll
      for (int e = 0; e < 8; ++e) cnt[e] += (ea == e) + (ebx == e);
    }
#pragma unroll
    for (int e = 0; e < 8; ++e) {
      int a = cnt[e];
#pragma unroll
      for (int s = 32; s; s >>= 1) a += __shfl_xor(a, s);
      cnt[e] = a;
    }
    if (lane == 0) {
#pragma unroll
      for (int e = 0; e < 8; ++e) hw[wv][e] = cnt[e];
    }
    {
      int ue = tid >> 5, ul = tid & 31;
      float a = 0.f;
#pragma unroll
      for (int k = 0; k < 16; ++k) a += g_usage_part[ue * RBLK + ul + k * 32];
#pragma unroll
      for (int s = 16; s; s >>= 1) a += __shfl_xor(a, s);
      if (ul == 0) su[ue] = a;
    }
#pragma unroll
    for (int k = 0; k < 9; ++k) {
      int gi = wv + k * 4;
      float a = 0.f;
#pragma unroll
      for (int q = 0; q < 8; ++q) a += g_gram_part[gi * RBLK + lane + q * 64];
#pragma unroll
      for (int s = 32; s; s >>= 1) a += __shfl_xor(a, s);
      if (lane == 0) sg[gi] = a;
    }
    __syncthreads();
    if (tid < 8) {
      int h = hw[0][tid] + hw[1][tid] + hw[2][tid] + hw[3][tid];
      hist[tid] = h;
      s_nt[tid] = (h + 127) >> 7;  // 128-row M-slots
      s_placed[tid] = 0;
      out_util[tid] = (float)h * (1.f / 8192.f);
    }
    __syncthreads();
    if (tid == 0) {
      float dv = 0.f;
#pragma unroll
      for (int e = 0; e < 8; ++e) {
        float u = su[e] * (1.f / 8192.f) - 0.125f;
        dv += u * u;
      }
      out_lbl[0] = dv * 0.125f;
      for (int p = 0; p < 136; ++p) {
        int e = p & 7;
        if (s_placed[e] >= s_nt[e]) {
          e = -1;
          for (int f = 0; f < 8; ++f)
            if (s_placed[f] < s_nt[f]) { e = f; break; }
        }
        unsigned v = 0xFFFFFFFFu;
        if (e >= 0) {
          v = ((unsigned)e << 16) | (unsigned)s_placed[e];
          s_placed[e] = s_placed[e] + 1;
        }
        g_tile[p] = v;
      }
    }
    if (tid < 64) {
      float ds = 0.f;
      if (tid < 28) {
        int c = tid, i = 0;
        while (c >= 7 - i) { c -= 7 - i; ++i; }
        int j = i + 1 + c;
        auto tri = [](int a2, int b2) {
          return a2 * 8 - (a2 * (a2 - 1)) / 2 + (b2 - a2);
        };
        float d2 = sg[tri(i, i)] + sg[tri(j, j)] - 2.f * sg[tri(i, j)];
        ds = sqrtf(fmaxf(d2, 0.f));
      }
#pragma unroll
      for (int s = 16; s; s >>= 1) ds += __shfl_xor(ds, s);
      if (tid == 0) out_div[0] = ds * (1.f / 28.f);
    }
    return;
  }
  // ---------------- list build path (blocks 0..7) ----------------
  const int e = blockIdx.x;
  unsigned recs[32];
#pragma unroll
  for (int c = 0; c < 32; ++c) recs[c] = g_e01[c * 256 + tid];
  __shared__ int wcnt[2][4];
  int base = 0;
#pragma unroll
  for (int c = 0; c < 32; ++c) {
    const int t = c * 256 + tid;
    unsigned rec = recs[c];
    int m0 = (int)(rec & 255u) == e;
    int m1 = (int)((rec >> 8) & 255u) == e;
    unsigned long long bal = __ballot(m0 || m1);
    int rank = __popcll(bal & ((1ull << lane) - 1ull));
    if (lane == 0) wcnt[c & 1][wv] = __popcll(bal);
    __syncthreads();
    int pre = base;
#pragma unroll
    for (int i = 0; i < 4; ++i)
      if (i < wv) pre += wcnt[c & 1][i];
    int tot = wcnt[c & 1][0] + wcnt[c & 1][1] + wcnt[c & 1][2] + wcnt[c & 1][3];
    if (m0 || m1) {
      int idx = pre + rank;
      g_ptok[e * PCAP + idx] = (t << 1) | (m1 ? 1 : 0);
      g_pw[e * PCAP + idx] = m1 ? g_w1[t] : g_w0[t];
    }
    base += tot;
  }
  if (tid == 0) g_cnt[e] = base;
}

// ---------------------------------------------------------------------------
// Grouped GEMM, 128x128 tile, BK=64, 8 waves, A-ONLY LDS dbuf (32 KB ->
// 3-4 blocks/CU), B read DIRECT from global (expert-affine -> same-XCD L2;
// fully coalesced 64B lines; halves LDS-read traffic, which R19's counters
// showed was the binding ceiling). __syncthreads dbuf (m97 pattern — safe
// with high TLP), XOR-swizzled A, XCD-affine worklist. bf16 epilogue.
// ---------------------------------------------------------------------------
__global__ __launch_bounds__(512) void k_gemm(const float* __restrict__ eb) {
  const unsigned tl = g_tile[blockIdx.x];
  if (tl == 0xFFFFFFFFu) return;
  const int e = tl >> 16;
  const int count = g_cnt[e];
  const int m0 = (tl & 0xffffu) * 128;
  if (m0 >= count) return;
  const int n0 = blockIdx.y * 128;

  __shared__ __align__(16) u16 As[2][128 * 64];  // 2 x 16 KB (A only)

  const int tid = threadIdx.x;
  const int lane = tid & 63;
  const int w = tid >> 6;
  const int wm = w >> 2, wn = w & 3;  // 2 m-halves x 4 n-quarters
  const int col16 = lane & 15, rg = lane >> 4;

  const int* ptok = g_ptok + e * PCAP;

  // A staging: 2 chunks/thread (16KB tile = 512 thr x 2 x 16B), swizzled src
  const u16* srcA[2];
  unsigned soff[2];
#pragma unroll
  for (int c = 0; c < 2; ++c) {
    int o = c * 8192 + tid * 16;  // byte offset within 16KB tile
    int row = o >> 7;             // 128 B per row (64 bf16)
    int sl = (o >> 4) & 7;
    int r = m0 + row;
    if (r > count - 1) r = count - 1;
    int tk = (ptok[r] >> 1) & (NTOK - 1);
    srcA[c] = g_xb + (size_t)tk * DDIM + ((sl ^ (row & 7)) << 3);
    soff[c] = (unsigned)o;  // linear LDS dest
  }

  // B global bases for this wave's two 16-row fragments (read per K-step)
  const u16* gB0 = g_wbf + (size_t)e * (FDIM * DDIM) +
                   (size_t)(n0 + wn * 32 + col16) * DDIM;
  const u16* gB1 = gB0 + (size_t)16 * DDIM;

#define STAGE(buf, k0)                                                        \
  {                                                                           \
    _Pragma("unroll") for (int c = 0; c < 2; ++c)                             \
        gload_lds16((const char*)(srcA[c] + (k0)), (char*)As[buf] + soff[c]); \
  }

  f32x4 acc[4][2];
  const f32x4 zz = {0.f, 0.f, 0.f, 0.f};
#pragma unroll
  for (int i = 0; i < 4; ++i)
#pragma unroll
    for (int j = 0; j < 2; ++j) acc[i][j] = zz;

  STAGE(0, 0);

  const int sxor = col16 & 7;
  for (int kk = 0; kk < 16; ++kk) {
    const int cur = kk & 1;
    __syncthreads();  // drains STAGE(cur); all waves done reading As[cur^1]
    if (kk < 15) STAGE(cur ^ 1, (kk + 1) * 64);  // prefetch under compute
#pragma unroll
    for (int ki = 0; ki < 2; ++ki) {
      bf16x8 af[4], bg[2];
      bg[0] = *(const bf16x8*)(gB0 + kk * 64 + ki * 32 + rg * 8);
      bg[1] = *(const bf16x8*)(gB1 + kk * 64 + ki * 32 + rg * 8);
#pragma unroll
      for (int mi = 0; mi < 4; ++mi) {
        int row = wm * 64 + mi * 16 + col16;
        af[mi] = *(const bf16x8*)(As[cur] + row * 64 +
                                  (((ki * 4 + rg) ^ sxor) << 3));
      }
      __builtin_amdgcn_s_setprio(1);
#pragma unroll
      for (int mi = 0; mi < 4; ++mi)
#pragma unroll
        for (int ni = 0; ni < 2; ++ni)
          acc[mi][ni] = __builtin_amdgcn_mfma_f32_16x16x32_bf16(
              af[mi], bg[ni], acc[mi][ni], 0, 0, 0);
      __builtin_amdgcn_s_setprio(0);
    }
  }
#undef STAGE

  // epilogue: bf16 stores of w*(acc+bias) into k=0 / k=1 buffers
#pragma unroll
  for (int mi = 0; mi < 4; ++mi) {
#pragma unroll
    for (int j = 0; j < 4; ++j) {
      int r = m0 + wm * 64 + mi * 16 + rg * 4 + j;
      if (r < count) {
        int enc = ptok[r];
        int tk = (enc >> 1) & (NTOK - 1);
        float wgt = g_pw[e * PCAP + r];
        u16* dst = (enc & 1 ? g_buf1 : g_buf0) + (size_t)tk * FDIM + n0 +
                   wn * 32 + col16;
        const float* bias = eb + e * FDIM + n0 + wn * 32 + col16;
#pragma unroll
        for (int ni = 0; ni < 2; ++ni)
          dst[ni * 16] = f2bf(wgt * (acc[mi][ni][j] + bias[ni * 16]));
      }
    }
  }
}

// ---------------------------------------------------------------------------
// Combine: out = buf0 + buf1 (bf16 + bf16 -> f32). 8 elems per iteration.
// ---------------------------------------------------------------------------
__global__ __launch_bounds__(256) void k_combine(float4* __restrict__ o, int n8) {
  const uint4* a = (const uint4*)g_buf0;
  const uint4* b = (const uint4*)g_buf1;
  int i = blockIdx.x * 256 + threadIdx.x;
  int stride = gridDim.x * 256;
  for (; i < n8; i += stride) {
    uint4 va = a[i], vb = b[i];
    float4 lo, hi;
    lo.x = b2f(va.x & 0xffffu) + b2f(vb.x & 0xffffu);
    lo.y = b2f(va.x >> 16) + b2f(vb.x >> 16);
    lo.z = b2f(va.y & 0xffffu) + b2f(vb.y & 0xffffu);
    lo.w = b2f(va.y >> 16) + b2f(vb.y >> 16);
    hi.x = b2f(va.z & 0xffffu) + b2f(vb.z & 0xffffu);
    hi.y = b2f(va.z >> 16) + b2f(vb.z >> 16);
    hi.z = b2f(va.w & 0xffffu) + b2f(vb.w & 0xffffu);
    hi.w = b2f(va.w >> 16) + b2f(vb.w >> 16);
    o[(size_t)i * 2] = lo;
    o[(size_t)i * 2 + 1] = hi;
  }
}

// ---------------------------------------------------------------------------
extern "C" void kernel_launch(void* const* d_in, const int* in_sizes, int n_in,
                              void* d_out, int out_size, void* d_ws,
                              size_t ws_size, hipStream_t stream) {
  const float* x = (const float*)d_in[0];
  const float* rwg = (const float*)d_in[1];
  const float* rb = (const float*)d_in[2];
  const float* ew = (const float*)d_in[3];
  const float* eb = (const float*)d_in[4];
  const float* ep = (const float*)d_in[5];

  float* out = (float*)d_out;  // output dtype is FLOAT32
  float* out_final = out;                          // [8192,1024]
  float* out_rw = out + (size_t)NTOK * FDIM;       // [8192,8]
  float* out_util = out_rw + (size_t)NTOK * NEXP;  // [8]
  float* out_lbl = out_util + NEXP;                // [1]
  float* out_div = out_lbl + 1;                    // [1]

  k_pre<<<1024, 256, 0, stream>>>(x, rwg, rb, ew, eb, ep, out_rw);
  k_lists<<<9, 256, 0, stream>>>(out_util, out_lbl, out_div);
  k_gemm<<<dim3(136, 8), 512, 0, stream>>>(eb);
  k_combine<<<2048, 256, 0, stream>>>((float4*)out_final, (NTOK * FDIM) / 8);
}

// Round 22
// 127.283 us; speedup vs baseline: 1.3414x; 1.3414x over previous
//
#include <hip/hip_runtime.h>
#include <stdint.h>

typedef unsigned short u16;
typedef __attribute__((ext_vector_type(4))) float f32x4;
typedef __attribute__((ext_vector_type(8))) short bf16x8;

#define NTOK 8192
#define DDIM 1024
#define FDIM 1024
#define NEXP 8
#define PCAP 8192
#define RBLK 512  // router sub-grid

// ---- device-global scratch -------------------------------------------------
__device__ __align__(256) u16 g_xb[NTOK * DDIM];          // x cast to bf16
__device__ __align__(256) u16 g_wbf[NEXP * FDIM * DDIM];  // expert_w bf16
__device__ __align__(256) u16 g_buf0[NTOK * FDIM];        // k=0 contrib (bf16)
__device__ __align__(256) u16 g_buf1[NTOK * FDIM];        // k=1 contrib (bf16)
__device__ __align__(256) int g_ptok[NEXP * PCAP];
__device__ __align__(256) float g_pw[NEXP * PCAP];
__device__ __align__(256) unsigned g_e01[NTOK];  // packed e0|e1<<8
__device__ __align__(256) float g_w0[NTOK];      // renorm top1 weight
__device__ __align__(256) float g_w1[NTOK];      // renorm top2 weight
__device__ __align__(256) float g_usage_part[NEXP * RBLK];  // [e][block]
__device__ __align__(256) float g_gram_part[36 * RBLK];     // [gi][block]
__device__ __align__(256) unsigned g_tile[160];  // XCD-affine worklist
__device__ int g_cnt[16];

__device__ __forceinline__ u16 f2bf(float f) {
  unsigned u = __builtin_bit_cast(unsigned, f);
  unsigned r = u + 0x7fffu + ((u >> 16) & 1u);  // RNE
  return (u16)(r >> 16);
}

__device__ __forceinline__ float b2f(unsigned h) {
  return __builtin_bit_cast(float, h << 16);
}

__device__ __forceinline__ void gload_lds16(const void* g, void* l) {
  __builtin_amdgcn_global_load_lds(
      (const __attribute__((address_space(1))) void*)g,
      (__attribute__((address_space(3))) void*)l, 16, 0, 0);
}

// ---------------------------------------------------------------------------
// Fused pre-pass. Blocks 0..511: router. Blocks 512..1023: gram + cast.
// Partials written TRANSPOSED: [entry][block] for coalesced reduction.
// ---------------------------------------------------------------------------
__global__ __launch_bounds__(256) void k_pre(const float* __restrict__ x,
                                             const float* __restrict__ rwg,
                                             const float* __restrict__ rb,
                                             const float* __restrict__ ew,
                                             const float* __restrict__ ebias,
                                             const float* __restrict__ epref,
                                             float* __restrict__ rwout) {
  const int tid = threadIdx.x;
  if (blockIdx.x >= RBLK) {
    // ---------------- gram + cast path ----------------
    const int bid = blockIdx.x - RBLK;
    const int P0 = FDIM * DDIM;
    const int PT = P0 + FDIM + DDIM;
    float g[36];
#pragma unroll
    for (int i = 0; i < 36; ++i) g[i] = 0.f;
    for (int k = bid * 256 + tid; k < PT; k += RBLK * 256) {
      float v[8];
      if (k < P0) {
#pragma unroll
        for (int e = 0; e < 8; ++e) v[e] = ew[(size_t)e * P0 + k];
#pragma unroll
        for (int e = 0; e < 8; ++e) g_wbf[(size_t)e * P0 + k] = f2bf(v[e]);
      } else if (k < P0 + FDIM) {
        int kk = k - P0;
#pragma unroll
        for (int e = 0; e < 8; ++e) v[e] = ebias[e * FDIM + kk];
      } else {
        int kk = k - P0 - FDIM;
#pragma unroll
        for (int e = 0; e < 8; ++e) v[e] = epref[e * DDIM + kk];
      }
      int idx = 0;
#pragma unroll
      for (int i = 0; i < 8; ++i)
#pragma unroll
        for (int j = i; j < 8; ++j) {
          g[idx] += v[i] * v[j];
          ++idx;
        }
    }
#pragma unroll
    for (int i = 0; i < 36; ++i) {
      float a = g[i];
#pragma unroll
      for (int s = 32; s; s >>= 1) a += __shfl_xor(a, s);
      g[i] = a;
    }
    __shared__ float gs[4][36];
    const int w = tid >> 6, lane = tid & 63;
    if (lane == 0) {
#pragma unroll
      for (int i = 0; i < 36; ++i) gs[w][i] = g[i];
    }
    __syncthreads();
    if (tid < 36)
      g_gram_part[tid * RBLK + bid] =
          gs[0][tid] + gs[1][tid] + gs[2][tid] + gs[3][tid];
    return;
  }
  // ---------------- router path ----------------
  __shared__ __align__(16) float rw_lds[NEXP * DDIM];
  __shared__ float us[NEXP];
  const int w = tid >> 6, lane = tid & 63;
  {
    const float4* src = (const float4*)rwg;
    float4* dst = (float4*)rw_lds;
#pragma unroll
    for (int i = 0; i < 8; ++i) dst[tid + 256 * i] = src[tid + 256 * i];
  }
  if (tid < NEXP) us[tid] = 0.f;
  __syncthreads();

  float rbl[NEXP];
#pragma unroll
  for (int e = 0; e < NEXP; ++e) rbl[e] = rb[e];
  float uw[NEXP];
#pragma unroll
  for (int e = 0; e < NEXP; ++e) uw[e] = 0.f;

  for (int it = 0; it < 4; ++it) {
    const int t = blockIdx.x * 16 + w * 4 + it;
    const float4* xv = (const float4*)(x + (size_t)t * DDIM);
    float4 xv4[4];
#pragma unroll
    for (int j = 0; j < 4; ++j) xv4[j] = xv[lane + 64 * j];
    ushort4* xo = (ushort4*)(g_xb + (size_t)t * DDIM);
#pragma unroll
    for (int j = 0; j < 4; ++j) {
      float4 v = xv4[j];
      ushort4 o;
      o.x = f2bf(v.x); o.y = f2bf(v.y); o.z = f2bf(v.z); o.w = f2bf(v.w);
      xo[lane + 64 * j] = o;
    }
    float lg[NEXP];
#pragma unroll
    for (int e = 0; e < NEXP; ++e) {
      float a = 0.f;
#pragma unroll
      for (int j = 0; j < 4; ++j) {
        float4 r = *(const float4*)&rw_lds[e * DDIM + (lane + 64 * j) * 4];
        float4 v = xv4[j];
        a += v.x * r.x + v.y * r.y + v.z * r.z + v.w * r.w;
      }
      lg[e] = a;
    }
#pragma unroll
    for (int e = 0; e < NEXP; ++e) {
      float a = lg[e];
#pragma unroll
      for (int s = 32; s; s >>= 1) a += __shfl_xor(a, s);
      lg[e] = a + rbl[e];
    }
    float mx = lg[0];
#pragma unroll
    for (int e = 1; e < NEXP; ++e) mx = fmaxf(mx, lg[e]);
    float p[NEXP];
    float sm = 0.f;
#pragma unroll
    for (int e = 0; e < NEXP; ++e) {
      p[e] = expf(lg[e] - mx);
      sm += p[e];
    }
    float inv = 1.f / sm;
#pragma unroll
    for (int e = 0; e < NEXP; ++e) {
      p[e] *= inv;
      uw[e] += p[e];
    }
    int e0 = 0;
    float b0 = p[0];
#pragma unroll
    for (int e = 1; e < NEXP; ++e)
      if (p[e] > b0) { b0 = p[e]; e0 = e; }
    int e1 = -1;
    float b1 = -1.f;
#pragma unroll
    for (int e = 0; e < NEXP; ++e)
      if (e != e0 && p[e] > b1) { b1 = p[e]; e1 = e; }
    if (lane == 0) {
      float4* rw4 = (float4*)(rwout + (size_t)t * NEXP);
      rw4[0] = make_float4(p[0], p[1], p[2], p[3]);
      rw4[1] = make_float4(p[4], p[5], p[6], p[7]);
      float rn = 1.f / (b0 + b1);
      g_e01[t] = (unsigned)e0 | ((unsigned)e1 << 8);
      g_w0[t] = b0 * rn;
      g_w1[t] = b1 * rn;
    }
  }
  if (lane == 0) {
#pragma unroll
    for (int e = 0; e < NEXP; ++e) atomicAdd(&us[e], uw[e]);  // LDS atomic only
  }
  __syncthreads();
  if (tid < NEXP) g_usage_part[tid * RBLK + blockIdx.x] = us[tid];
}

// ---------------------------------------------------------------------------
// Blocks 0..7: list build (e01 preloaded to registers; double-buffered wcnt).
// Block 8: stats (unrolled coalesced reductions) + XCD-affine worklist
// (128-row M-slots).
// ---------------------------------------------------------------------------
__global__ __launch_bounds__(256) void k_lists(float* __restrict__ out_util,
                                               float* __restrict__ out_lbl,
                                               float* __restrict__ out_div) {
  const int tid = threadIdx.x;
  const int wv = tid >> 6, lane = tid & 63;
  if (blockIdx.x == 8) {
    __shared__ int hw[4][8];
    __shared__ int hist[8];
    __shared__ int s_nt[8], s_placed[8];
    __shared__ float su[8];
    __shared__ float sg[36];
    int cnt[8];
#pragma unroll
    for (int e = 0; e < 8; ++e) cnt[e] = 0;
#pragma unroll 8
    for (int t = tid; t < NTOK; t += 256) {
      unsigned rec = g_e01[t];
      int ea = (int)(rec & 255u), ebx = (int)((rec >> 8) & 255u);
#pragma unroll
      for (int e = 0; e < 8; ++e) cnt[e] += (ea == e) + (ebx == e);
    }
#pragma unroll
    for (int e = 0; e < 8; ++e) {
      int a = cnt[e];
#pragma unroll
      for (int s = 32; s; s >>= 1) a += __shfl_xor(a, s);
      cnt[e] = a;
    }
    if (lane == 0) {
#pragma unroll
      for (int e = 0; e < 8; ++e) hw[wv][e] = cnt[e];
    }
    {
      int ue = tid >> 5, ul = tid & 31;
      float a = 0.f;
#pragma unroll
      for (int k = 0; k < 16; ++k) a += g_usage_part[ue * RBLK + ul + k * 32];
#pragma unroll
      for (int s = 16; s; s >>= 1) a += __shfl_xor(a, s);
      if (ul == 0) su[ue] = a;
    }
#pragma unroll
    for (int k = 0; k < 9; ++k) {
      int gi = wv + k * 4;
      float a = 0.f;
#pragma unroll
      for (int q = 0; q < 8; ++q) a += g_gram_part[gi * RBLK + lane + q * 64];
#pragma unroll
      for (int s = 32; s; s >>= 1) a += __shfl_xor(a, s);
      if (lane == 0) sg[gi] = a;
    }
    __syncthreads();
    if (tid < 8) {
      int h = hw[0][tid] + hw[1][tid] + hw[2][tid] + hw[3][tid];
      hist[tid] = h;
      s_nt[tid] = (h + 127) >> 7;  // 128-row M-slots
      s_placed[tid] = 0;
      out_util[tid] = (float)h * (1.f / 8192.f);
    }
    __syncthreads();
    if (tid == 0) {
      float dv = 0.f;
#pragma unroll
      for (int e = 0; e < 8; ++e) {
        float u = su[e] * (1.f / 8192.f) - 0.125f;
        dv += u * u;
      }
      out_lbl[0] = dv * 0.125f;
      for (int p = 0; p < 136; ++p) {
        int e = p & 7;
        if (s_placed[e] >= s_nt[e]) {
          e = -1;
          for (int f = 0; f < 8; ++f)
            if (s_placed[f] < s_nt[f]) { e = f; break; }
        }
        unsigned v = 0xFFFFFFFFu;
        if (e >= 0) {
          v = ((unsigned)e << 16) | (unsigned)s_placed[e];
          s_placed[e] = s_placed[e] + 1;
        }
        g_tile[p] = v;
      }
    }
    if (tid < 64) {
      float ds = 0.f;
      if (tid < 28) {
        int c = tid, i = 0;
        while (c >= 7 - i) { c -= 7 - i; ++i; }
        int j = i + 1 + c;
        auto tri = [](int a2, int b2) {
          return a2 * 8 - (a2 * (a2 - 1)) / 2 + (b2 - a2);
        };
        float d2 = sg[tri(i, i)] + sg[tri(j, j)] - 2.f * sg[tri(i, j)];
        ds = sqrtf(fmaxf(d2, 0.f));
      }
#pragma unroll
      for (int s = 16; s; s >>= 1) ds += __shfl_xor(ds, s);
      if (tid == 0) out_div[0] = ds * (1.f / 28.f);
    }
    return;
  }
  // ---------------- list build path (blocks 0..7) ----------------
  const int e = blockIdx.x;
  unsigned recs[32];
#pragma unroll
  for (int c = 0; c < 32; ++c) recs[c] = g_e01[c * 256 + tid];
  __shared__ int wcnt[2][4];
  int base = 0;
#pragma unroll
  for (int c = 0; c < 32; ++c) {
    const int t = c * 256 + tid;
    unsigned rec = recs[c];
    int m0 = (int)(rec & 255u) == e;
    int m1 = (int)((rec >> 8) & 255u) == e;
    unsigned long long bal = __ballot(m0 || m1);
    int rank = __popcll(bal & ((1ull << lane) - 1ull));
    if (lane == 0) wcnt[c & 1][wv] = __popcll(bal);
    __syncthreads();
    int pre = base;
#pragma unroll
    for (int i = 0; i < 4; ++i)
      if (i < wv) pre += wcnt[c & 1][i];
    int tot = wcnt[c & 1][0] + wcnt[c & 1][1] + wcnt[c & 1][2] + wcnt[c & 1][3];
    if (m0 || m1) {
      int idx = pre + rank;
      g_ptok[e * PCAP + idx] = (t << 1) | (m1 ? 1 : 0);
      g_pw[e * PCAP + idx] = m1 ? g_w1[t] : g_w0[t];
    }
    base += tot;
  }
  if (tid == 0) g_cnt[e] = base;
}

// ---------------------------------------------------------------------------
// Grouped GEMM, R19 geometry (128x128, BK=64, 8 waves, per-wave 64x32,
// dbuf 64 KB, XOR-swizzle, XCD-affine worklist) with the catalog 2-phase
// schedule: STAGE(next) BEFORE compute, then vmcnt(0)+ONE barrier per
// K-step (loads fly under ds_read+MFMA; half the barriers of R19).
// ---------------------------------------------------------------------------
__global__ __launch_bounds__(512) void k_gemm(const float* __restrict__ eb) {
  const unsigned tl = g_tile[blockIdx.x];
  if (tl == 0xFFFFFFFFu) return;
  const int e = tl >> 16;
  const int count = g_cnt[e];
  const int m0 = (tl & 0xffffu) * 128;
  if (m0 >= count) return;
  const int n0 = blockIdx.y * 128;

  __shared__ __align__(16) u16 As[2][128 * 64];  // 2 x 16 KB
  __shared__ __align__(16) u16 Bs[2][128 * 64];  // 2 x 16 KB

  const int tid = threadIdx.x;
  const int lane = tid & 63;
  const int w = tid >> 6;
  const int wm = w >> 2, wn = w & 3;  // 2 m-halves x 4 n-quarters
  const int col16 = lane & 15, rg = lane >> 4;

  const int* ptok = g_ptok + e * PCAP;

  const u16* srcA[2];
  const u16* srcB[2];
  unsigned soff[2];
#pragma unroll
  for (int c = 0; c < 2; ++c) {
    int o = c * 8192 + tid * 16;  // byte offset within 16KB tile
    int row = o >> 7;             // 128 B per row (64 bf16)
    int sl = (o >> 4) & 7;
    int r = m0 + row;
    if (r > count - 1) r = count - 1;
    int tk = (ptok[r] >> 1) & (NTOK - 1);
    srcA[c] = g_xb + (size_t)tk * DDIM + ((sl ^ (row & 7)) << 3);
    srcB[c] = g_wbf + (size_t)e * (FDIM * DDIM) + (size_t)(n0 + row) * DDIM +
              ((sl ^ (row & 7)) << 3);
    soff[c] = (unsigned)o;  // linear LDS dest
  }

#define STAGE(buf, k0)                                                        \
  {                                                                           \
    _Pragma("unroll") for (int c = 0; c < 2; ++c)                             \
        gload_lds16((const char*)(srcA[c] + (k0)), (char*)As[buf] + soff[c]); \
    _Pragma("unroll") for (int c = 0; c < 2; ++c)                             \
        gload_lds16((const char*)(srcB[c] + (k0)), (char*)Bs[buf] + soff[c]); \
  }

  f32x4 acc[4][2];
  const f32x4 zz = {0.f, 0.f, 0.f, 0.f};
#pragma unroll
  for (int i = 0; i < 4; ++i)
#pragma unroll
    for (int j = 0; j < 2; ++j) acc[i][j] = zz;

  // prologue: tile 0 -> buf 0, wait, barrier
  STAGE(0, 0);
  asm volatile("s_waitcnt vmcnt(0)" ::: "memory");
  __builtin_amdgcn_s_barrier();

  const int sxor = col16 & 7;
  for (int kk = 0; kk < 16; ++kk) {
    const int cur = kk & 1;
    // issue next-tile loads FIRST; they fly under this tile's compute.
    // WAR-safe: buf[cur^1] held tile kk-1; all waves passed the end-of-
    // iter kk-1 barrier (after computing it) before reaching here.
    if (kk < 15) STAGE(cur ^ 1, (kk + 1) * 64);

#pragma unroll
    for (int ki = 0; ki < 2; ++ki) {
      bf16x8 af[4], bg[2];
#pragma unroll
      for (int mi = 0; mi < 4; ++mi) {
        int row = wm * 64 + mi * 16 + col16;
        af[mi] = *(const bf16x8*)(As[cur] + row * 64 +
                                  (((ki * 4 + rg) ^ sxor) << 3));
      }
#pragma unroll
      for (int ni = 0; ni < 2; ++ni) {
        int row = wn * 32 + ni * 16 + col16;
        bg[ni] = *(const bf16x8*)(Bs[cur] + row * 64 +
                                  (((ki * 4 + rg) ^ sxor) << 3));
      }
      __builtin_amdgcn_s_setprio(1);
#pragma unroll
      for (int mi = 0; mi < 4; ++mi)
#pragma unroll
        for (int ni = 0; ni < 2; ++ni)
          acc[mi][ni] = __builtin_amdgcn_mfma_f32_16x16x32_bf16(
              af[mi], bg[ni], acc[mi][ni], 0, 0, 0);
      __builtin_amdgcn_s_setprio(0);
    }

    // next tile's loads have landed (they had the whole compute to fly)
    asm volatile("s_waitcnt vmcnt(0)" ::: "memory");
    __builtin_amdgcn_s_barrier();  // single barrier per K-step
  }
#undef STAGE

  // epilogue: bf16 stores of w*(acc+bias) into k=0 / k=1 buffers
#pragma unroll
  for (int mi = 0; mi < 4; ++mi) {
#pragma unroll
    for (int j = 0; j < 4; ++j) {
      int r = m0 + wm * 64 + mi * 16 + rg * 4 + j;
      if (r < count) {
        int enc = ptok[r];
        int tk = (enc >> 1) & (NTOK - 1);
        float wgt = g_pw[e * PCAP + r];
        u16* dst = (enc & 1 ? g_buf1 : g_buf0) + (size_t)tk * FDIM + n0 +
                   wn * 32 + col16;
        const float* bias = eb + e * FDIM + n0 + wn * 32 + col16;
#pragma unroll
        for (int ni = 0; ni < 2; ++ni)
          dst[ni * 16] = f2bf(wgt * (acc[mi][ni][j] + bias[ni * 16]));
      }
    }
  }
}

// ---------------------------------------------------------------------------
// Combine: out = buf0 + buf1 (bf16 + bf16 -> f32). 8 elems per iteration.
// ---------------------------------------------------------------------------
__global__ __launch_bounds__(256) void k_combine(float4* __restrict__ o, int n8) {
  const uint4* a = (const uint4*)g_buf0;
  const uint4* b = (const uint4*)g_buf1;
  int i = blockIdx.x * 256 + threadIdx.x;
  int stride = gridDim.x * 256;
  for (; i < n8; i += stride) {
    uint4 va = a[i], vb = b[i];
    float4 lo, hi;
    lo.x = b2f(va.x & 0xffffu) + b2f(vb.x & 0xffffu);
    lo.y = b2f(va.x >> 16) + b2f(vb.x >> 16);
    lo.z = b2f(va.y & 0xffffu) + b2f(vb.y & 0xffffu);
    lo.w = b2f(va.y >> 16) + b2f(vb.y >> 16);
    hi.x = b2f(va.z & 0xffffu) + b2f(vb.z & 0xffffu);
    hi.y = b2f(va.z >> 16) + b2f(vb.z >> 16);
    hi.z = b2f(va.w & 0xffffu) + b2f(vb.w & 0xffffu);
    hi.w = b2f(va.w >> 16) + b2f(vb.w >> 16);
    o[(size_t)i * 2] = lo;
    o[(size_t)i * 2 + 1] = hi;
  }
}

// ---------------------------------------------------------------------------
extern "C" void kernel_launch(void* const* d_in, const int* in_sizes, int n_in,
                              void* d_out, int out_size, void* d_ws,
                              size_t ws_size, hipStream_t stream) {
  const float* x = (const float*)d_in[0];
  const float* rwg = (const float*)d_in[1];
  const float* rb = (const float*)d_in[2];
  const float* ew = (const float*)d_in[3];
  const float* eb = (const float*)d_in[4];
  const float* ep = (const float*)d_in[5];

  float* out = (float*)d_out;  // output dtype is FLOAT32
  float* out_final = out;                          // [8192,1024]
  float* out_rw = out + (size_t)NTOK * FDIM;       // [8192,8]
  float* out_util = out_rw + (size_t)NTOK * NEXP;  // [8]
  float* out_lbl = out_util + NEXP;                // [1]
  float* out_div = out_lbl + 1;                    // [1]

  k_pre<<<1024, 256, 0, stream>>>(x, rwg, rb, ew, eb, ep, out_rw);
  k_lists<<<9, 256, 0, stream>>>(out_util, out_lbl, out_div);
  k_gemm<<<dim3(136, 8), 512, 0, stream>>>(eb);
  k_combine<<<2048, 256, 0, stream>>>((float4*)out_final, (NTOK * FDIM) / 8);
}